// Round 2
// baseline (444.822 us; speedup 1.0000x reference)
//
#include <hip/hip_runtime.h>
#include <hip/hip_bf16.h>

#define E_ 8
#define D_ 1024
#define H_ 4096
#define T_ 512
#define A_ 1024  // total assignments = T_ * top_k

typedef __attribute__((ext_vector_type(8))) short bf16x8;
typedef __attribute__((ext_vector_type(4))) float f32x4;

__device__ __forceinline__ unsigned short f2bf(float f) {
  __hip_bfloat16 h = __float2bfloat16(f);
  return *reinterpret_cast<unsigned short*>(&h);
}

__device__ __forceinline__ bf16x8 cvt8(float4 lo, float4 hi) {
  bf16x8 r;
  r[0] = (short)f2bf(lo.x); r[1] = (short)f2bf(lo.y);
  r[2] = (short)f2bf(lo.z); r[3] = (short)f2bf(lo.w);
  r[4] = (short)f2bf(hi.x); r[5] = (short)f2bf(hi.y);
  r[6] = (short)f2bf(hi.z); r[7] = (short)f2bf(hi.w);
  return r;
}

// ---------------- Router: logits -> softmax -> top2 -> renorm; x -> bf16 ----
__global__ void moe_router(const float* __restrict__ x,
                           const float* __restrict__ gw,
                           unsigned short* __restrict__ xb,
                           int* __restrict__ sel,
                           float* __restrict__ wtop) {
  const int t = blockIdx.x;
  const int lane = threadIdx.x;  // 64 threads
  const float* xr = x + (size_t)t * D_;

  for (int i = lane; i < D_; i += 64) xb[(size_t)t * D_ + i] = f2bf(xr[i]);

  float lg[E_];
  for (int e = 0; e < E_; ++e) {
    const float* g = gw + (size_t)e * D_;
    float p = 0.f;
    for (int i = lane; i < D_; i += 64) p += xr[i] * g[i];
#pragma unroll
    for (int off = 32; off; off >>= 1) p += __shfl_xor(p, off);
    lg[e] = p;
  }
  if (lane == 0) {
    float m = lg[0];
    for (int e = 1; e < E_; ++e) m = fmaxf(m, lg[e]);
    float pr[E_];
    float s = 0.f;
    for (int e = 0; e < E_; ++e) { pr[e] = __expf(lg[e] - m); s += pr[e]; }
    const float inv = 1.f / s;
    for (int e = 0; e < E_; ++e) pr[e] *= inv;
    float v0 = -1.f, v1 = -1.f; int i0 = 0, i1 = 0;
    for (int e = 0; e < E_; ++e) {
      float p = pr[e];
      if (p > v0)      { v1 = v0; i1 = i0; v0 = p; i0 = e; }
      else if (p > v1) { v1 = p; i1 = e; }
    }
    const float s2 = 1.f / (v0 + v1);
    sel[2 * t] = i0; sel[2 * t + 1] = i1;
    wtop[2 * t] = v0 * s2; wtop[2 * t + 1] = v1 * s2;
  }
}

// ---------------- Compaction: deterministic, order-preserving ---------------
__global__ void moe_compact(const int* __restrict__ sel,
                            const float* __restrict__ wtop,
                            int* __restrict__ counts,
                            int* __restrict__ offsets,
                            int* __restrict__ tok,
                            int* __restrict__ slotof,
                            float* __restrict__ coef) {
  const int tid = threadIdx.x;         // 512 threads = 8 waves
  const int e = tid >> 6;              // wave id = expert
  const int lane = tid & 63;
  __shared__ int cnt[E_], offs[E_];

  int base = 0;
  for (int c = 0; c < T_ / 64; ++c) {
    const int t = c * 64 + lane;
    const int s0 = sel[2 * t], s1 = sel[2 * t + 1];
    const bool f = (s0 == e) || (s1 == e);
    unsigned long long b = __ballot(f);
    base += __popcll(b);
  }
  if (lane == 0) cnt[e] = base;
  __syncthreads();
  if (tid == 0) {
    int o = 0;
    for (int i = 0; i < E_; ++i) { offs[i] = o; o += cnt[i]; }
  }
  __syncthreads();
  if (lane == 0) { counts[e] = cnt[e]; offsets[e] = offs[e]; }

  int pos = offs[e];
  for (int c = 0; c < T_ / 64; ++c) {
    const int t = c * 64 + lane;
    const int s0 = sel[2 * t], s1 = sel[2 * t + 1];
    const bool f = (s0 == e) || (s1 == e);
    unsigned long long b = __ballot(f);
    const int myp = pos + __popcll(b & ((1ull << lane) - 1ull));
    if (f) {
      const int k = (s0 == e) ? 0 : 1;
      tok[myp] = t;
      slotof[2 * t + k] = myp;
      coef[myp] = wtop[2 * t + k];
    }
    pos += __popcll(b);
  }
}

// ---------------- FFN1: barrier-free, weights streamed direct to regs ------
// Block = 4 waves; wave owns 128 tokens x 16 h-cols. No LDS, no barriers.
#define LOAD1(aS, b1S, b3S, KT) do {                                          \
    _Pragma("unroll")                                                         \
    for (int m = 0; m < 8; ++m)                                               \
      aS[m] = *reinterpret_cast<const bf16x8*>(rowp[m] + (KT));               \
    b1S[0] = *reinterpret_cast<const float4*>(w1p + (KT));                    \
    b1S[1] = *reinterpret_cast<const float4*>(w1p + (KT) + 4);                \
    b3S[0] = *reinterpret_cast<const float4*>(w3p + (KT));                    \
    b3S[1] = *reinterpret_cast<const float4*>(w3p + (KT) + 4);                \
  } while (0)

#define COMP1(aS, b1S, b3S) do {                                              \
    bf16x8 b1f = cvt8(b1S[0], b1S[1]);                                        \
    bf16x8 b3f = cvt8(b3S[0], b3S[1]);                                        \
    _Pragma("unroll")                                                         \
    for (int m = 0; m < 8; ++m) {                                             \
      acc1[m] = __builtin_amdgcn_mfma_f32_16x16x32_bf16(aS[m], b1f, acc1[m], 0, 0, 0); \
      acc3[m] = __builtin_amdgcn_mfma_f32_16x16x32_bf16(aS[m], b3f, acc3[m], 0, 0, 0); \
    }                                                                         \
  } while (0)

__launch_bounds__(256, 2)
__global__ void moe_ffn1(const unsigned short* __restrict__ xb,
                         const float* __restrict__ w1,
                         const float* __restrict__ w3,
                         const int* __restrict__ counts,
                         const int* __restrict__ offsets,
                         const int* __restrict__ tok,
                         unsigned short* __restrict__ act) {
  const int bid = blockIdx.x;
  const int hg = bid & 63;            // 64 h-groups of 64 cols
  const int mt = (bid >> 6) & 3;      // 4 m-tiles of 128 rows
  const int e  = bid >> 8;
  const int count = counts[e];
  if (mt * 128 >= count) return;
  const int off = offsets[e];

  const int tid = threadIdx.x;
  const int lane = tid & 63, wid = tid >> 6;
  const int lr = lane & 15, kg = lane >> 4;
  const int hbase = hg * 64 + wid * 16;

  // Per-lane token row pointers (clamped), pre-offset by k-group
  const unsigned short* rowp[8];
#pragma unroll
  for (int m = 0; m < 8; ++m) {
    int mrow = mt * 128 + m * 16 + lr;
    int cr = mrow < count ? mrow : count - 1;
    rowp[m] = xb + (size_t)tok[off + cr] * D_ + kg * 8;
  }
  const float* w1p = w1 + ((size_t)e * H_ + hbase + lr) * D_ + kg * 8;
  const float* w3p = w3 + ((size_t)e * H_ + hbase + lr) * D_ + kg * 8;

  f32x4 acc1[8] = {};
  f32x4 acc3[8] = {};

  bf16x8 aA[8], aB[8];
  float4 b1A[2], b3A[2], b1B[2], b3B[2];

  LOAD1(aA, b1A, b3A, 0);
  for (int kt = 0; kt < D_; kt += 64) {
    LOAD1(aB, b1B, b3B, kt + 32);
    COMP1(aA, b1A, b3A);
    if (kt + 64 < D_) LOAD1(aA, b1A, b3A, kt + 64);
    COMP1(aB, b1B, b3B);
  }

  // Epilogue: silu(h1)*h3 -> bf16 act
  const int rbase = kg * 4;
  const int hcol = hbase + lr;
#pragma unroll
  for (int m = 0; m < 8; ++m) {
#pragma unroll
    for (int r = 0; r < 4; ++r) {
      const int mrow = mt * 128 + m * 16 + rbase + r;
      if (mrow < count) {
        const float h1 = acc1[m][r];
        const float h3 = acc3[m][r];
        const float a = h1 / (1.f + __expf(-h1)) * h3;
        act[(size_t)(off + mrow) * H_ + hcol] = f2bf(a);
      }
    }
  }
}

// ---------------- FFN2: barrier-free, optional K-split ---------------------
#define LOAD2(aS, bS, KT) do {                                                \
    _Pragma("unroll")                                                         \
    for (int m = 0; m < 8; ++m)                                               \
      aS[m] = *reinterpret_cast<const bf16x8*>(rowp[m] + (KT));               \
    bS[0] = *reinterpret_cast<const float4*>(w2p + (KT));                     \
    bS[1] = *reinterpret_cast<const float4*>(w2p + (KT) + 4);                 \
  } while (0)

#define COMP2(aS, bS) do {                                                    \
    bf16x8 bf = cvt8(bS[0], bS[1]);                                           \
    _Pragma("unroll")                                                         \
    for (int m = 0; m < 8; ++m)                                               \
      acc[m] = __builtin_amdgcn_mfma_f32_16x16x32_bf16(aS[m], bf, acc[m], 0, 0, 0); \
  } while (0)

__launch_bounds__(256, 2)
__global__ void moe_ffn2(const unsigned short* __restrict__ act,
                         const float* __restrict__ w2,
                         const int* __restrict__ counts,
                         const int* __restrict__ offsets,
                         const float* __restrict__ coef,
                         float* __restrict__ part,
                         int ksn) {
  int b = blockIdx.x;
  const int dg = b & 15; b >>= 4;     // 16 d-groups of 64 cols
  const int mt = b & 3;  b >>= 2;     // 4 m-tiles of 128 rows
  const int e  = b & 7;  b >>= 3;
  const int ks = b;                   // K-split index
  const int count = counts[e];
  if (mt * 128 >= count) return;
  const int off = offsets[e];

  const int tid = threadIdx.x;
  const int lane = tid & 63, wid = tid >> 6;
  const int lr = lane & 15, kg = lane >> 4;
  const int dbase = dg * 64 + wid * 16;
  const int KS = H_ / ksn;
  const int kbase = ks * KS;

  const unsigned short* rowp[8];
#pragma unroll
  for (int m = 0; m < 8; ++m) {
    int mrow = mt * 128 + m * 16 + lr;
    int cr = mrow < count ? mrow : count - 1;
    rowp[m] = act + (size_t)(off + cr) * H_ + kbase + kg * 8;
  }
  const float* w2p = w2 + ((size_t)e * D_ + dbase + lr) * H_ + kbase + kg * 8;

  f32x4 acc[8] = {};
  bf16x8 aA[8], aB[8];
  float4 bA[2], bB[2];

  LOAD2(aA, bA, 0);
  for (int kt = 0; kt < KS; kt += 64) {
    LOAD2(aB, bB, kt + 32);
    COMP2(aA, bA);
    if (kt + 64 < KS) LOAD2(aA, bA, kt + 64);
    COMP2(aB, bB);
  }

  const int rbase = kg * 4;
  const int dcol = dbase + lr;
  float* pbase = part + (size_t)ks * A_ * D_;
#pragma unroll
  for (int m = 0; m < 8; ++m) {
#pragma unroll
    for (int r = 0; r < 4; ++r) {
      const int mrow = mt * 128 + m * 16 + rbase + r;
      if (mrow < count) {
        const float cf = coef[off + mrow];
        pbase[(size_t)(off + mrow) * D_ + dcol] = cf * acc[m][r];
      }
    }
  }
}

// out[t] = sum over partials in fixed order -> deterministic
__global__ void moe_combine(const float* __restrict__ part,
                            const int* __restrict__ slotof,
                            float* __restrict__ out,
                            int ksn) {
  const int t = blockIdx.x;
  const int i = threadIdx.x;  // 256 threads, float4 each
  const int g0 = slotof[2 * t], g1 = slotof[2 * t + 1];
  float4 a = reinterpret_cast<const float4*>(part + (size_t)g0 * D_)[i];
  float4 b = reinterpret_cast<const float4*>(part + (size_t)g1 * D_)[i];
  float4 o;
  o.x = a.x + b.x; o.y = a.y + b.y; o.z = a.z + b.z; o.w = a.w + b.w;
  if (ksn == 2) {
    const float* p1 = part + (size_t)A_ * D_;
    float4 c = reinterpret_cast<const float4*>(p1 + (size_t)g0 * D_)[i];
    float4 d = reinterpret_cast<const float4*>(p1 + (size_t)g1 * D_)[i];
    o.x += c.x + d.x; o.y += c.y + d.y; o.z += c.z + d.z; o.w += c.w + d.w;
  }
  reinterpret_cast<float4*>(out + (size_t)t * D_)[i] = o;
}

extern "C" void kernel_launch(void* const* d_in, const int* in_sizes, int n_in,
                              void* d_out, int out_size, void* d_ws, size_t ws_size,
                              hipStream_t stream) {
  const float* x  = (const float*)d_in[0];
  const float* gw = (const float*)d_in[1];
  const float* w1 = (const float*)d_in[2];
  const float* w3 = (const float*)d_in[3];
  const float* w2 = (const float*)d_in[4];
  float* out = (float*)d_out;

  // K-split of ffn2 doubles `part`; use it only if ws is big enough.
  const size_t MB = 1024 * 1024;
  const int ksn = (ws_size >= 17 * MB) ? 2 : 1;

  char* ws = (char*)d_ws;
  // Layout (temporal overlap: xb's region is reused by `part`, which is only
  // written by ffn2 after ffn1 has fully consumed xb — same-stream ordering):
  //   [0, ksn*4MB)            part   (written by ffn2, read by combine)
  //   [0, 1MB)                xb     (written by router, read by ffn1)
  //   [ksn*4MB, +8MB)         act    (written by ffn1, read by ffn2)
  //   [ksn*4MB+8MB, +24KB)    small arrays (live router..combine)
  float* part = (float*)(ws);
  unsigned short* xb = (unsigned short*)(ws);
  unsigned short* act = (unsigned short*)(ws + (size_t)ksn * 4 * MB);
  char* sm = ws + (size_t)ksn * 4 * MB + 8 * MB;
  int*   sel     = (int*)  (sm);
  float* wtop    = (float*)(sm + 4096);
  int*   counts  = (int*)  (sm + 8192);
  int*   offsets = (int*)  (sm + 8192 + 64);
  int*   tokl    = (int*)  (sm + 12288);
  int*   slotof  = (int*)  (sm + 16384);
  float* coef    = (float*)(sm + 20480);

  moe_router <<<T_, 64, 0, stream>>>(x, gw, xb, sel, wtop);
  moe_compact<<<1, 512, 0, stream>>>(sel, wtop, counts, offsets, tokl, slotof, coef);
  moe_ffn1   <<<E_ * 4 * 64, 256, 0, stream>>>(xb, w1, w3, counts, offsets, tokl, act);
  moe_ffn2   <<<E_ * 4 * 16 * ksn, 256, 0, stream>>>(act, w2, counts, offsets, coef, part, ksn);
  moe_combine<<<T_, 256, 0, stream>>>(part, slotof, out, ksn);
}

// Round 3
// 123.332 us; speedup vs baseline: 3.6067x; 3.6067x over previous
//
#include <hip/hip_runtime.h>
#include <hip/hip_bf16.h>

#define E_ 8
#define D_ 1024
#define H_ 4096
#define T_ 512
#define A_ 1024  // total assignments = T_ * top_k

typedef __attribute__((ext_vector_type(8))) short bf16x8;
typedef __attribute__((ext_vector_type(4))) float f32x4;
typedef __attribute__((ext_vector_type(8))) unsigned short u16x8;

__device__ __forceinline__ unsigned short f2bf(float f) {
  __hip_bfloat16 h = __float2bfloat16(f);
  return *reinterpret_cast<unsigned short*>(&h);
}

__device__ __forceinline__ u16x8 pack8(float4 a, float4 b) {
  u16x8 r;
  r[0] = f2bf(a.x); r[1] = f2bf(a.y); r[2] = f2bf(a.z); r[3] = f2bf(a.w);
  r[4] = f2bf(b.x); r[5] = f2bf(b.y); r[6] = f2bf(b.z); r[7] = f2bf(b.w);
  return r;
}

// ---------------- Router: logits -> softmax -> top2 -> renorm; x -> bf16 ----
__global__ void moe_router(const float* __restrict__ x,
                           const float* __restrict__ gw,
                           unsigned short* __restrict__ xb,
                           int* __restrict__ sel,
                           float* __restrict__ wtop) {
  const int t = blockIdx.x;
  const int lane = threadIdx.x;  // 64
  const float* xr = x + (size_t)t * D_;

  float4 xv[4];
#pragma unroll
  for (int i = 0; i < 4; ++i) xv[i] = *reinterpret_cast<const float4*>(xr + (i * 64 + lane) * 4);
#pragma unroll
  for (int i = 0; i < 4; ++i) {
    ushort4 u;
    u.x = f2bf(xv[i].x); u.y = f2bf(xv[i].y); u.z = f2bf(xv[i].z); u.w = f2bf(xv[i].w);
    *reinterpret_cast<ushort4*>(xb + (size_t)t * D_ + (i * 64 + lane) * 4) = u;
  }

  float lg[E_];
  for (int e = 0; e < E_; ++e) {
    const float* g = gw + (size_t)e * D_;
    float p = 0.f;
#pragma unroll
    for (int i = 0; i < 4; ++i) {
      float4 gv = *reinterpret_cast<const float4*>(g + (i * 64 + lane) * 4);
      p += xv[i].x * gv.x + xv[i].y * gv.y + xv[i].z * gv.z + xv[i].w * gv.w;
    }
#pragma unroll
    for (int off = 32; off; off >>= 1) p += __shfl_xor(p, off);
    lg[e] = p;
  }
  if (lane == 0) {
    float m = lg[0];
    for (int e = 1; e < E_; ++e) m = fmaxf(m, lg[e]);
    float pr[E_];
    float s = 0.f;
    for (int e = 0; e < E_; ++e) { pr[e] = __expf(lg[e] - m); s += pr[e]; }
    const float inv = 1.f / s;
    for (int e = 0; e < E_; ++e) pr[e] *= inv;
    float v0 = -1.f, v1 = -1.f; int i0 = 0, i1 = 0;
    for (int e = 0; e < E_; ++e) {
      float p = pr[e];
      if (p > v0)      { v1 = v0; i1 = i0; v0 = p; i0 = e; }
      else if (p > v1) { v1 = p; i1 = e; }
    }
    const float s2 = 1.f / (v0 + v1);
    sel[2 * t] = i0; sel[2 * t + 1] = i1;
    wtop[2 * t] = v0 * s2; wtop[2 * t + 1] = v1 * s2;
  }
}

// ---------------- Compaction: deterministic, order-preserving ---------------
__global__ void moe_compact(const int* __restrict__ sel,
                            const float* __restrict__ wtop,
                            int* __restrict__ counts,
                            int* __restrict__ offsets,
                            int* __restrict__ tok,
                            int* __restrict__ slotof,
                            float* __restrict__ coef) {
  const int tid = threadIdx.x;  // 512 = 8 waves; wave = expert
  const int e = tid >> 6;
  const int lane = tid & 63;
  __shared__ int cnt[E_], offs[E_];

  int base = 0;
  for (int c = 0; c < T_ / 64; ++c) {
    const int t = c * 64 + lane;
    const bool f = (sel[2 * t] == e) || (sel[2 * t + 1] == e);
    base += __popcll(__ballot(f));
  }
  if (lane == 0) cnt[e] = base;
  __syncthreads();
  if (tid == 0) {
    int o = 0;
    for (int i = 0; i < E_; ++i) { offs[i] = o; o += cnt[i]; }
  }
  __syncthreads();
  if (lane == 0) { counts[e] = cnt[e]; offsets[e] = offs[e]; }

  int pos = offs[e];
  for (int c = 0; c < T_ / 64; ++c) {
    const int t = c * 64 + lane;
    const int s0 = sel[2 * t], s1 = sel[2 * t + 1];
    const bool f = (s0 == e) || (s1 == e);
    unsigned long long b = __ballot(f);
    const int myp = pos + __popcll(b & ((1ull << lane) - 1ull));
    if (f) {
      const int k = (s0 == e) ? 0 : 1;
      tok[myp] = t;
      slotof[2 * t + k] = myp;
      coef[myp] = wtop[2 * t + k];
    }
    pos += __popcll(b);
  }
}

// ---------------- FFN kernels: barrier-staged grouped GEMM ------------------
// BM=192 covers count<=192 in one tile (outer m0 loop for safety).
// 4 waves split M (48 rows each). BN=64, BK=64. Padded LDS [.][72].
#define BM_ 192
#define LDA_ 72

__launch_bounds__(256, 2)
__global__ void moe_ffn1(const unsigned short* __restrict__ xb,
                         const float* __restrict__ w1,
                         const float* __restrict__ w3,
                         const int* __restrict__ counts,
                         const int* __restrict__ offsets,
                         const int* __restrict__ tok,
                         unsigned short* __restrict__ act) {
  const int bid = blockIdx.x;
  const int hg = bid & 63;
  const int e = bid >> 6;
  const int count = counts[e];
  if (count <= 0) return;
  const int off = offsets[e];

  __shared__ unsigned short As[BM_][LDA_];
  __shared__ unsigned short B1s[64][LDA_];
  __shared__ unsigned short B3s[64][LDA_];

  const int tid = threadIdx.x;
  const int lane = tid & 63, wid = tid >> 6;
  const int lr = lane & 15, kg = lane >> 4;
  const int wm = wid * 48;
  const int hbase = hg * 64;

  const int brow = tid >> 2, bcol = (tid & 3) * 16;
  const float* W1p = w1 + ((size_t)e * H_ + hbase + brow) * D_ + bcol;
  const float* W3p = w3 + ((size_t)e * H_ + hbase + brow) * D_ + bcol;

  for (int m0 = 0; m0 < count; m0 += BM_) {
    const int mc = count - m0;
    const unsigned short* arow[6];
#pragma unroll
    for (int i = 0; i < 6; ++i) {
      const int r = i * 32 + (tid >> 3);
      const int cr = (m0 + r < count) ? (m0 + r) : (count - 1);
      arow[i] = xb + (size_t)tok[off + cr] * D_ + (tid & 7) * 8;
    }
    const int q = mc - wm;
    const int mfn = (q <= 0) ? 0 : ((q + 15) >> 4 < 3 ? (q + 15) >> 4 : 3);

    f32x4 acc1[3][4] = {};
    f32x4 acc3[3][4] = {};

    for (int kt = 0; kt < D_; kt += 64) {
      __syncthreads();
      u16x8 av[6];
#pragma unroll
      for (int i = 0; i < 6; ++i) av[i] = *reinterpret_cast<const u16x8*>(arow[i] + kt);
      float4 b1v[4], b3v[4];
#pragma unroll
      for (int i = 0; i < 4; ++i) {
        b1v[i] = *reinterpret_cast<const float4*>(W1p + kt + i * 4);
        b3v[i] = *reinterpret_cast<const float4*>(W3p + kt + i * 4);
      }
#pragma unroll
      for (int i = 0; i < 6; ++i)
        *reinterpret_cast<u16x8*>(&As[i * 32 + (tid >> 3)][(tid & 7) * 8]) = av[i];
#pragma unroll
      for (int i = 0; i < 2; ++i) {
        *reinterpret_cast<u16x8*>(&B1s[brow][bcol + i * 8]) = pack8(b1v[2 * i], b1v[2 * i + 1]);
        *reinterpret_cast<u16x8*>(&B3s[brow][bcol + i * 8]) = pack8(b3v[2 * i], b3v[2 * i + 1]);
      }
      __syncthreads();

#pragma unroll
      for (int ks = 0; ks < 2; ++ks) {
        const int kc = ks * 32 + kg * 8;
        bf16x8 af[3];
#pragma unroll
        for (int mf = 0; mf < 3; ++mf)
          af[mf] = *reinterpret_cast<const bf16x8*>(&As[wm + mf * 16 + lr][kc]);
#pragma unroll
        for (int nf = 0; nf < 4; ++nf) {
          bf16x8 b1f = *reinterpret_cast<const bf16x8*>(&B1s[nf * 16 + lr][kc]);
          bf16x8 b3f = *reinterpret_cast<const bf16x8*>(&B3s[nf * 16 + lr][kc]);
#pragma unroll
          for (int mf = 0; mf < 3; ++mf)
            if (mf < mfn) {
              acc1[mf][nf] = __builtin_amdgcn_mfma_f32_16x16x32_bf16(af[mf], b1f, acc1[mf][nf], 0, 0, 0);
              acc3[mf][nf] = __builtin_amdgcn_mfma_f32_16x16x32_bf16(af[mf], b3f, acc3[mf][nf], 0, 0, 0);
            }
        }
      }
    }

#pragma unroll
    for (int mf = 0; mf < 3; ++mf) {
#pragma unroll
      for (int r = 0; r < 4; ++r) {
        const int mrow = m0 + wm + mf * 16 + kg * 4 + r;
        if (mrow < count) {
          const size_t rb = (size_t)(off + mrow) * H_;
#pragma unroll
          for (int nf = 0; nf < 4; ++nf) {
            const float h1 = acc1[mf][nf][r];
            const float h3 = acc3[mf][nf][r];
            const float a = h1 / (1.f + __expf(-h1)) * h3;
            act[rb + hbase + nf * 16 + lr] = f2bf(a);
          }
        }
      }
    }
  }
}

__launch_bounds__(256, 2)
__global__ void moe_ffn2(const unsigned short* __restrict__ act,
                         const float* __restrict__ w2,
                         const int* __restrict__ counts,
                         const int* __restrict__ offsets,
                         const float* __restrict__ coef,
                         float* __restrict__ part,
                         int kschunk) {
  const int bid = blockIdx.x;
  const int ks = bid >> 7;
  const int e = (bid >> 4) & 7;
  const int dg = bid & 15;
  const int count = counts[e];
  if (count <= 0) return;
  const int off = offsets[e];
  const int kbase = ks * kschunk;

  __shared__ unsigned short As[BM_][LDA_];
  __shared__ unsigned short Bs[64][LDA_];

  const int tid = threadIdx.x;
  const int lane = tid & 63, wid = tid >> 6;
  const int lr = lane & 15, kg = lane >> 4;
  const int wm = wid * 48;
  const int dbase = dg * 64;

  const int brow = tid >> 2, bcol = (tid & 3) * 16;
  const float* W2p = w2 + ((size_t)e * D_ + dbase + brow) * H_ + kbase + bcol;

  for (int m0 = 0; m0 < count; m0 += BM_) {
    const int mc = count - m0;
    const unsigned short* arow[6];
#pragma unroll
    for (int i = 0; i < 6; ++i) {
      const int r = i * 32 + (tid >> 3);
      const int cr = (m0 + r < count) ? (m0 + r) : (count - 1);
      arow[i] = act + (size_t)(off + cr) * H_ + kbase + (tid & 7) * 8;
    }
    const int q = mc - wm;
    const int mfn = (q <= 0) ? 0 : ((q + 15) >> 4 < 3 ? (q + 15) >> 4 : 3);

    f32x4 acc[3][4] = {};

    for (int kt = 0; kt < kschunk; kt += 64) {
      __syncthreads();
      u16x8 av[6];
#pragma unroll
      for (int i = 0; i < 6; ++i) av[i] = *reinterpret_cast<const u16x8*>(arow[i] + kt);
      float4 bv[4];
#pragma unroll
      for (int i = 0; i < 4; ++i) bv[i] = *reinterpret_cast<const float4*>(W2p + kt + i * 4);
#pragma unroll
      for (int i = 0; i < 6; ++i)
        *reinterpret_cast<u16x8*>(&As[i * 32 + (tid >> 3)][(tid & 7) * 8]) = av[i];
#pragma unroll
      for (int i = 0; i < 2; ++i)
        *reinterpret_cast<u16x8*>(&Bs[brow][bcol + i * 8]) = pack8(bv[2 * i], bv[2 * i + 1]);
      __syncthreads();

#pragma unroll
      for (int ks2 = 0; ks2 < 2; ++ks2) {
        const int kc = ks2 * 32 + kg * 8;
        bf16x8 af[3];
#pragma unroll
        for (int mf = 0; mf < 3; ++mf)
          af[mf] = *reinterpret_cast<const bf16x8*>(&As[wm + mf * 16 + lr][kc]);
#pragma unroll
        for (int nf = 0; nf < 4; ++nf) {
          bf16x8 bf = *reinterpret_cast<const bf16x8*>(&Bs[nf * 16 + lr][kc]);
#pragma unroll
          for (int mf = 0; mf < 3; ++mf)
            if (mf < mfn)
              acc[mf][nf] = __builtin_amdgcn_mfma_f32_16x16x32_bf16(af[mf], bf, acc[mf][nf], 0, 0, 0);
        }
      }
    }

#pragma unroll
    for (int mf = 0; mf < 3; ++mf) {
#pragma unroll
      for (int r = 0; r < 4; ++r) {
        const int mrow = m0 + wm + mf * 16 + kg * 4 + r;
        if (mrow < count) {
          const float cf = coef[off + mrow];
          float* prow = part + ((size_t)ks * A_ + off + mrow) * D_;
#pragma unroll
          for (int nf = 0; nf < 4; ++nf)
            prow[dbase + nf * 16 + lr] = cf * acc[mf][nf][r];
        }
      }
    }
  }
}

// out[t] = sum over (ksn x 2 slots) partials in fixed order -> deterministic
__global__ void moe_combine(const float* __restrict__ part,
                            const int* __restrict__ slotof,
                            float* __restrict__ out,
                            int ksn) {
  const int t = blockIdx.x;
  const int i = threadIdx.x;  // 256 threads, float4 each
  const int g0 = slotof[2 * t], g1 = slotof[2 * t + 1];
  float4 o = make_float4(0.f, 0.f, 0.f, 0.f);
  for (int ks = 0; ks < ksn; ++ks) {
    const float* p = part + (size_t)ks * A_ * D_;
    float4 a = reinterpret_cast<const float4*>(p + (size_t)g0 * D_)[i];
    float4 b = reinterpret_cast<const float4*>(p + (size_t)g1 * D_)[i];
    o.x += a.x + b.x; o.y += a.y + b.y; o.z += a.z + b.z; o.w += a.w + b.w;
  }
  reinterpret_cast<float4*>(out + (size_t)t * D_)[i] = o;
}

extern "C" void kernel_launch(void* const* d_in, const int* in_sizes, int n_in,
                              void* d_out, int out_size, void* d_ws, size_t ws_size,
                              hipStream_t stream) {
  const float* x  = (const float*)d_in[0];
  const float* gw = (const float*)d_in[1];
  const float* w1 = (const float*)d_in[2];
  const float* w3 = (const float*)d_in[3];
  const float* w2 = (const float*)d_in[4];
  float* out = (float*)d_out;

  char* ws = (char*)d_ws;
  const size_t SM   = 32768;
  const size_t ACT  = (size_t)A_ * H_ * 2;   // 8 MB bf16
  const size_t XB   = (size_t)T_ * D_ * 2;   // 1 MB bf16
  const size_t P1   = (size_t)A_ * D_ * 4;   // 4 MB fp32 per K-split

  char* sm = ws;
  unsigned short* act = (unsigned short*)(ws + SM);
  unsigned short* xb  = (unsigned short*)(ws + SM + ACT);
  float* part         = (float*)(ws + SM + ACT + XB);
  const size_t base = SM + ACT + XB;
  const int ksn = (ws_size >= base + 4 * P1) ? 4 : (ws_size >= base + 2 * P1) ? 2 : 1;

  int*   sel     = (int*)  (sm);
  float* wtop    = (float*)(sm + 4096);
  int*   counts  = (int*)  (sm + 8192);
  int*   offsets = (int*)  (sm + 8192 + 64);
  int*   tokl    = (int*)  (sm + 12288);
  int*   slotof  = (int*)  (sm + 16384);
  float* coef    = (float*)(sm + 20480);

  moe_router <<<T_, 64, 0, stream>>>(x, gw, xb, sel, wtop);
  moe_compact<<<1, 512, 0, stream>>>(sel, wtop, counts, offsets, tokl, slotof, coef);
  moe_ffn1   <<<E_ * 64, 256, 0, stream>>>(xb, w1, w3, counts, offsets, tokl, act);
  moe_ffn2   <<<128 * ksn, 256, 0, stream>>>(act, w2, counts, offsets, coef, part, H_ / ksn);
  moe_combine<<<T_, 256, 0, stream>>>(part, slotof, out, ksn);
}